// Round 7
// baseline (955.188 us; speedup 1.0000x reference)
//
#include <hip/hip_runtime.h>
#include <hip/hip_bf16.h>
#include <math.h>

typedef __bf16 bf16x8 __attribute__((ext_vector_type(8)));
typedef float floatx4 __attribute__((ext_vector_type(4)));

__device__ __forceinline__ short f2b(float f) {
  __hip_bfloat16 h = __float2bfloat16(f);
  return *reinterpret_cast<short*>(&h);
}
__device__ __forceinline__ float b2f(short s) {
  unsigned u = ((unsigned)(unsigned short)s) << 16;
  float f;
  __builtin_memcpy(&f, &u, 4);
  return f;
}

// async global->LDS, 16B per lane; lds base must be wave-uniform (HW adds lane*16)
__device__ __forceinline__ void gl2lds16(const void* g, void* l) {
  __builtin_amdgcn_global_load_lds((__attribute__((address_space(1))) const void*)g,
                                   (__attribute__((address_space(3))) void*)l, 16, 0, 0);
}

// ---------------- block reduction helper ----------------
__device__ __forceinline__ float block_sum(float v, float* sdata) {
#pragma unroll
  for (int o = 32; o > 0; o >>= 1) v += __shfl_down(v, o, 64);
  __syncthreads();
  int lane = threadIdx.x & 63, wid = threadIdx.x >> 6;
  if (lane == 0) sdata[wid] = v;
  __syncthreads();
  float s = 0.f;
  int nw = blockDim.x >> 6;
  for (int i = 0; i < nw; i++) s += sdata[i];
  return s;
}

// ---------------- conversion kernels ----------------
__global__ void cvt4_kernel(const float* __restrict__ s0, short* __restrict__ d0, long n0,
                            const float* __restrict__ s1, short* __restrict__ d1, long n1,
                            const float* __restrict__ s2, short* __restrict__ d2, long n2,
                            const float* __restrict__ s3, short* __restrict__ d3, long n3) {
  long i = (long)blockIdx.x * blockDim.x + threadIdx.x;
  const float* s;
  short* d;
  long j;
  if (i < n0) { s = s0; d = d0; j = i; }
  else if (i < n0 + n1) { s = s1; d = d1; j = i - n0; }
  else if (i < n0 + n1 + n2) { s = s2; d = d2; j = i - n0 - n1; }
  else if (i < n0 + n1 + n2 + n3) { s = s3; d = d3; j = i - n0 - n1 - n2; }
  else return;
  float4 v = ((const float4*)s)[j];
  short4 o;
  o.x = f2b(v.x); o.y = f2b(v.y); o.z = f2b(v.z); o.w = f2b(v.w);
  ((short4*)d)[j] = o;
}

// dst[c*ldD + r] = bf16(src[r*ldS + c]); grid (C/32, R/32, nb), block (32,8)
__global__ void cvtT2_kernel(const float* __restrict__ src, short* __restrict__ dst,
                             int ldS, int ldD, long sS, long sD) {
  src += (size_t)blockIdx.z * sS;
  dst += (size_t)blockIdx.z * sD;
  __shared__ float tile[32][33];
  int r0 = blockIdx.y * 32, c0 = blockIdx.x * 32;
  int tx = threadIdx.x, ty = threadIdx.y;
#pragma unroll
  for (int i = 0; i < 32; i += 8)
    tile[ty + i][tx] = src[(size_t)(r0 + ty + i) * ldS + c0 + tx];
  __syncthreads();
#pragma unroll
  for (int i = 0; i < 32; i += 8)
    dst[(size_t)(c0 + ty + i) * ldD + r0 + tx] = f2b(tile[tx][ty + i]);
}

// build Bcat1 = [wtT ; wtc] (ld E) and Bcat2 = [wtcT | wt | wu] (ld 3E) per layer
__global__ void prep_trans_kernel(const float* __restrict__ Wt, const float* __restrict__ Wtc,
                                  const float* __restrict__ Wu,
                                  short* __restrict__ Bcat1, short* __restrict__ Bcat2, int E) {
  int d = blockIdx.z;
  const float* wt = Wt + (size_t)d * E * E;
  const float* wtc = Wtc + (size_t)d * E * E;
  const float* wu = Wu + (size_t)d * E * E;
  short* b1 = Bcat1 + (size_t)d * 2 * E * E;
  short* b2 = Bcat2 + (size_t)d * E * 3 * E;
  int E3 = 3 * E;
  __shared__ float t1[32][33], t2[32][33];
  int r0 = blockIdx.y * 32, c0 = blockIdx.x * 32;
  int tx = threadIdx.x, ty = threadIdx.y;
#pragma unroll
  for (int i = 0; i < 32; i += 8) {
    t1[ty + i][tx] = wt[(size_t)(r0 + ty + i) * E + c0 + tx];
    t2[ty + i][tx] = wtc[(size_t)(r0 + ty + i) * E + c0 + tx];
  }
  __syncthreads();
#pragma unroll
  for (int i = 0; i < 32; i += 8) {
    b1[(size_t)(c0 + ty + i) * E + r0 + tx] = f2b(t1[tx][ty + i]);
    b1[(size_t)(E + r0 + ty + i) * E + c0 + tx] = f2b(t2[ty + i][tx]);
    b2[(size_t)(c0 + ty + i) * E3 + r0 + tx] = f2b(t2[tx][ty + i]);
    b2[(size_t)(r0 + ty + i) * E3 + E + c0 + tx] = f2b(t1[ty + i][tx]);
    b2[(size_t)(r0 + ty + i) * E3 + 2 * E + c0 + tx] = f2b(wu[(size_t)(r0 + ty + i) * E + c0 + tx]);
  }
}

// ---------------- embed gather + norm; fills xsa, xsa_bf, xsaT_bf, z-slot of t3 -------
__global__ void embed_norm_kernel(const int* __restrict__ masked,
                                  const float* __restrict__ embed,
                                  float* __restrict__ xsa, short* __restrict__ xsa_bf,
                                  short* __restrict__ xsaT_bf, short* __restrict__ t3,
                                  int E, int L) {
  int row = blockIdx.x;
  int g = masked[row];
  __shared__ float sdata[8];
  float x = embed[(size_t)g * E + threadIdx.x];
  float mean = block_sum(x, sdata) / E;
  float d = x - mean;
  float var = block_sum(d * d, sdata) / (E - 1);
  float val = x / (1.0f + sqrtf(var));
  size_t off = (size_t)row * E + threadIdx.x;
  xsa[off] = val;
  short b = f2b(val);
  xsa_bf[off] = b;
  t3[(size_t)row * 3 * E + 2 * E + threadIdx.x] = b;
  int bb = row / L, l = row - bb * L;
  xsaT_bf[((size_t)bb * E + threadIdx.x) * L + l] = b;
}

// ---------------- bf16 MFMA GEMM (NT), async dbuf, XOR swizzle, tiled ----------------
template <int BM, int BN, int OUT_BF16>
__global__ __launch_bounds__(256) void bgemm_kernel(
    const short* __restrict__ A, int lda, long sA,
    const short* __restrict__ B, int ldb, long sB,
    void* __restrict__ Cv, int ldc, long sC,
    int Ksz, float alpha, const float* __restrict__ bias,
    int relu, int shiftA, int shiftB, int nsplit, int Lroll) {
  constexpr int WM = BM / 2, WN = BN / 2;
  constexpr int MT = WM / 16, NT = WN / 16;
  constexpr int NCH = (BM + BN) * 8;
  constexpr int LPT = NCH / 256;
  A += (size_t)blockIdx.z * sA;
  B += (size_t)blockIdx.z * sB;
  float* Cf = (float*)Cv + (size_t)blockIdx.z * sC;
  short* Cb = (short*)Cv + (size_t)blockIdx.z * sC;
  int m0 = blockIdx.y * BM, n0 = blockIdx.x * BN;
  int shift = (n0 < nsplit) ? shiftA : shiftB;
  __shared__ short S[2][(BM + BN) * 64];
  int tid = threadIdx.x, lane = tid & 63, w = tid >> 6;
  int wm = (w & 1) * WM, wn = (w >> 1) * WN;
  int ml = lane & 15, q4 = lane >> 4, sw = ml & 7;

  const short* src[LPT];
#pragma unroll
  for (int i = 0; i < LPT; i++) {
    int q = i * 256 + w * 64 + lane;
    if (q < BM * 8) {
      int m = q >> 3, cl = q & 7, cs = cl ^ (m & 7);
      int mg = m0 + m;
      if (shift != 0) {
        int bb = mg / Lroll, l = mg - bb * Lroll;
        l = (l + shift + Lroll) % Lroll;
        mg = bb * Lroll + l;
      }
      src[i] = A + (size_t)mg * lda + cs * 8;
    } else {
      int qb = q - BM * 8;
      int n = qb >> 3, cl = qb & 7, cs = cl ^ (n & 7);
      src[i] = B + (size_t)(n0 + n) * ldb + cs * 8;
    }
  }
#pragma unroll
  for (int i = 0; i < LPT; i++)
    gl2lds16(src[i], &S[0][(i * 256 + w * 64) * 8]);
  floatx4 acc[MT][NT] = {};
  int nT = Ksz >> 6;
  for (int t = 0; t < nT; t++) {
    __syncthreads();
    int cur = t & 1;
    if (t + 1 < nT) {
      int nxt = cur ^ 1, ko = (t + 1) * 64;
#pragma unroll
      for (int i = 0; i < LPT; i++)
        gl2lds16(src[i] + ko, &S[nxt][(i * 256 + w * 64) * 8]);
    }
#pragma unroll
    for (int kk = 0; kk < 2; kk++) {
      int j = kk * 4 + q4;
      bf16x8 af[MT], bg[NT];
#pragma unroll
      for (int mt = 0; mt < MT; mt++) {
        int r = wm + mt * 16 + ml;
        af[mt] = *reinterpret_cast<const bf16x8*>(&S[cur][r * 64 + (j ^ sw) * 8]);
      }
#pragma unroll
      for (int nt = 0; nt < NT; nt++) {
        int r = wn + nt * 16 + ml;
        bg[nt] = *reinterpret_cast<const bf16x8*>(&S[cur][BM * 64 + r * 64 + (j ^ sw) * 8]);
      }
#pragma unroll
      for (int mt = 0; mt < MT; mt++)
#pragma unroll
        for (int nt = 0; nt < NT; nt++)
          acc[mt][nt] = __builtin_amdgcn_mfma_f32_16x16x32_bf16(af[mt], bg[nt], acc[mt][nt], 0, 0, 0);
    }
  }
#pragma unroll
  for (int mt = 0; mt < MT; mt++)
#pragma unroll
    for (int nt = 0; nt < NT; nt++) {
      floatx4 v = acc[mt][nt];
#pragma unroll
      for (int r = 0; r < 4; r++) {
        int grow = m0 + wm + mt * 16 + q4 * 4 + r;
        int gcol = n0 + wn + nt * 16 + ml;
        float x = alpha * v[r];
        if (bias) x += bias[gcol];
        if (relu) x = fmaxf(x, 0.f);
        if (OUT_BF16)
          Cb[(size_t)grow * ldc + gcol] = f2b(x);
        else
          Cf[(size_t)grow * ldc + gcol] = x;
      }
    }
}

// ---------------- fused flash attention ----------------
// Per block: 64 query rows of one batch. Q [LK,E] bf16 (in-place Y), K = xsa_bf [L,E],
// Vt = xsaT_bf [E,L]. Online softmax in fp32; P via LDS in MFMA-A layout.
__global__ __launch_bounds__(256) void flash_kernel(
    short* __restrict__ Qy, const short* __restrict__ Kx, const short* __restrict__ Vt,
    float scale, int L, int E, int KH) {
  int b = blockIdx.y;
  int LK = L * KH;
  short* Q = Qy + (size_t)b * LK * E;
  const short* Kb = Kx + (size_t)b * L * E;
  const short* Vb = Vt + (size_t)b * E * L;
  int qr0 = blockIdx.x * 64;

  __shared__ short Ks[64 * 256];
  __shared__ short Vs[256 * 32];
  __shared__ short Ps[4][16 * 64];

  int tid = threadIdx.x, lane = tid & 63, w = tid >> 6;
  int ml = lane & 15, q4 = lane >> 4;

  // ---- stage Q tile (64x256) into Ks area, swizzled ----
#pragma unroll
  for (int i = 0; i < 8; i++) {
    int q = i * 256 + tid;
    int m = q >> 5, ec = q & 31;
    int ecs = (ec & 24) | ((ec & 7) ^ (m & 7));
    gl2lds16(Q + (size_t)(qr0 + m) * E + ecs * 8, &Ks[(i * 256 + w * 64) * 8]);
  }
  __syncthreads();
  bf16x8 qf[8];
#pragma unroll
  for (int kk = 0; kk < 8; kk++) {
    int ec = kk * 4 + q4;
    qf[kk] = *reinterpret_cast<const bf16x8*>(
        &Ks[(w * 16 + ml) * 256 + (ec & 24) * 8 + (((ec & 7) ^ (ml & 7))) * 8]);
  }
  __syncthreads();  // Q reads done -> Ks overwritable

  const short* kSrc[8];
#pragma unroll
  for (int i = 0; i < 8; i++) {
    int q = i * 256 + tid;
    int m = q >> 5, ec = q & 31;
    int ecs = (ec & 24) | ((ec & 7) ^ (m & 7));
    kSrc[i] = Kb + (size_t)m * E + ecs * 8;
  }
  const short* vSrc[4];
#pragma unroll
  for (int i = 0; i < 4; i++) {
    int q = i * 256 + tid;
    int e = q >> 2, cl = q & 3;
    int kc = cl ^ (e & 3);
    vSrc[i] = Vb + (size_t)e * L + kc * 8;
  }

#pragma unroll
  for (int i = 0; i < 8; i++) gl2lds16(kSrc[i], &Ks[(i * 256 + w * 64) * 8]);
#pragma unroll
  for (int i = 0; i < 4; i++) gl2lds16(vSrc[i], &Vs[(i * 256 + w * 64) * 8]);

  floatx4 oacc[16] = {};
  float mrun[4] = {-INFINITY, -INFINITY, -INFINITY, -INFINITY};
  float lrun[4] = {0.f, 0.f, 0.f, 0.f};

  int nTiles = L / 64;
  for (int t = 0; t < nTiles; t++) {
    __syncthreads();  // Ks(t), Vs(t,h0) visible
    floatx4 sacc[4] = {};
#pragma unroll
    for (int kk = 0; kk < 8; kk++) {
      int ec = kk * 4 + q4;
#pragma unroll
      for (int nt = 0; nt < 4; nt++) {
        int kr = nt * 16 + ml;
        bf16x8 bf = *reinterpret_cast<const bf16x8*>(
            &Ks[kr * 256 + (ec & 24) * 8 + (((ec & 7) ^ (ml & 7))) * 8]);
        sacc[nt] = __builtin_amdgcn_mfma_f32_16x16x32_bf16(qf[kk], bf, sacc[nt], 0, 0, 0);
      }
    }
    __syncthreads();  // all Ks reads done
    if (t + 1 < nTiles) {
      int ko = (t + 1) * 64 * E;
#pragma unroll
      for (int i = 0; i < 8; i++) gl2lds16(kSrc[i] + ko, &Ks[(i * 256 + w * 64) * 8]);
    }
    // online softmax (per-wave rows; scaled domain)
#pragma unroll
    for (int r = 0; r < 4; r++) {
      float mx = fmaxf(fmaxf(sacc[0][r], sacc[1][r]), fmaxf(sacc[2][r], sacc[3][r]));
#pragma unroll
      for (int o = 1; o < 16; o <<= 1) mx = fmaxf(mx, __shfl_xor(mx, o, 64));
      float mnew = fmaxf(mrun[r], mx * scale);
      float alpha = expf(mrun[r] - mnew);
      mrun[r] = mnew;
      lrun[r] *= alpha;
#pragma unroll
      for (int nto = 0; nto < 16; nto++) oacc[nto][r] *= alpha;
      int mrow = q4 * 4 + r;
      float s = 0.f;
#pragma unroll
      for (int nt = 0; nt < 4; nt++) {
        float p = expf(sacc[nt][r] * scale - mnew);
        s += p;
        int col = nt * 16 + ml;
        int cc = col >> 3;
        Ps[w][mrow * 64 + ((cc ^ (mrow & 7))) * 8 + (col & 7)] = f2b(p);
      }
#pragma unroll
      for (int o = 1; o < 16; o <<= 1) s += __shfl_xor(s, o, 64);
      lrun[r] += s;
    }
    // PV half 0 (keys 0-31 of tile)
    {
      int cc = q4;
      bf16x8 pf = *reinterpret_cast<const bf16x8*>(&Ps[w][ml * 64 + ((cc ^ (ml & 7))) * 8]);
#pragma unroll
      for (int nto = 0; nto < 16; nto++) {
        int e = nto * 16 + ml;
        bf16x8 vf = *reinterpret_cast<const bf16x8*>(&Vs[e * 32 + ((q4 ^ (e & 3))) * 8]);
        oacc[nto] = __builtin_amdgcn_mfma_f32_16x16x32_bf16(pf, vf, oacc[nto], 0, 0, 0);
      }
    }
    __syncthreads();  // Vs h0 reads done
    {
      int ko = t * 64 + 32;
#pragma unroll
      for (int i = 0; i < 4; i++) gl2lds16(vSrc[i] + ko, &Vs[(i * 256 + w * 64) * 8]);
    }
    __syncthreads();  // Vs h1 visible
    // PV half 1 (keys 32-63)
    {
      int cc = 4 + q4;
      bf16x8 pf = *reinterpret_cast<const bf16x8*>(&Ps[w][ml * 64 + ((cc ^ (ml & 7))) * 8]);
#pragma unroll
      for (int nto = 0; nto < 16; nto++) {
        int e = nto * 16 + ml;
        bf16x8 vf = *reinterpret_cast<const bf16x8*>(&Vs[e * 32 + ((q4 ^ (e & 3))) * 8]);
        oacc[nto] = __builtin_amdgcn_mfma_f32_16x16x32_bf16(pf, vf, oacc[nto], 0, 0, 0);
      }
    }
    if (t + 1 < nTiles) {
      __syncthreads();  // Vs h1 reads done
      int ko = (t + 1) * 64;
#pragma unroll
      for (int i = 0; i < 4; i++) gl2lds16(vSrc[i] + ko, &Vs[(i * 256 + w * 64) * 8]);
    }
  }
  // epilogue: Y = O / l (in-place over Q)
#pragma unroll
  for (int r = 0; r < 4; r++) {
    float inv = 1.f / lrun[r];
    int grow = qr0 + w * 16 + q4 * 4 + r;
#pragma unroll
    for (int nto = 0; nto < 16; nto++)
      Q[(size_t)grow * E + nto * 16 + ml] = f2b(oacc[nto][r] * inv);
  }
}

// ------- xsad=norm(xsad+xid); xsa=norm(xsa+0.05*xsad); write xsa fp32/bf16/bf16-T -----
__global__ void addnorm_kernel(const float* __restrict__ xsad,
                               const float* __restrict__ xid,
                               float* __restrict__ xsa, short* __restrict__ xsa_bf,
                               short* __restrict__ xsaT_bf, int E, int L) {
  int row = blockIdx.x, t = threadIdx.x;
  __shared__ float sdata[8];
  size_t off = (size_t)row * E + t;
  float s1 = xsad[off] + xid[off];
  float mean = block_sum(s1, sdata) / E;
  float d = s1 - mean;
  float var = block_sum(d * d, sdata) / (E - 1);
  float n1 = s1 / (1.f + sqrtf(var));
  float t2 = xsa[off] + 0.05f * n1;
  float mean2 = block_sum(t2, sdata) / E;
  float d2 = t2 - mean2;
  float var2 = block_sum(d2 * d2, sdata) / (E - 1);
  float res = t2 / (1.f + sqrtf(var2));
  xsa[off] = res;
  short b = f2b(res);
  xsa_bf[off] = b;
  int bb = row / L, l = row - bb * L;
  xsaT_bf[((size_t)bb * E + t) * L + l] = b;
}

// ---------------- gather masked positions (bf16) + targets ----------------
__global__ void gather_kernel(const float* __restrict__ xsa, const int* __restrict__ mask,
                              const int* __restrict__ unmasked,
                              short* __restrict__ lptok_bf, int* __restrict__ tgt,
                              int L, int LM, int E) {
  int bi = blockIdx.x;
  int b = bi / LM;
  int pos = mask[bi];
  float v = xsa[((size_t)b * L + pos) * E + threadIdx.x];
  lptok_bf[(size_t)bi * E + threadIdx.x] = f2b(v);
  if (threadIdx.x == 0) tgt[bi] = unmasked[b * L + pos];
}

// ---------------- head: MFMA logits + per-(row,128-chunk) max/sumexp ----------------
__global__ __launch_bounds__(256) void head_stats_kernel(
    const short* __restrict__ V, const short* __restrict__ Eb,
    float* __restrict__ stM, float* __restrict__ stS, int Ksz, int nch) {
  int m0 = blockIdx.y * 128, n0 = blockIdx.x * 128;
  __shared__ short As[2][8192];
  __shared__ short Bs[2][8192];
  int tid = threadIdx.x, lane = tid & 63, w = tid >> 6;
  int wm = (w & 1) * 64, wn = (w >> 1) * 64;
  int ml = lane & 15, q4 = lane >> 4, sw = ml & 7;
  const short* aSrc[4];
  const short* bSrc[4];
#pragma unroll
  for (int i = 0; i < 4; i++) {
    int q = i * 256 + w * 64 + lane;
    int m = q >> 3, cl = q & 7;
    int cs = cl ^ (m & 7);
    aSrc[i] = V + (size_t)(m0 + m) * Ksz + cs * 8;
    bSrc[i] = Eb + (size_t)(n0 + m) * Ksz + cs * 8;
  }
#pragma unroll
  for (int i = 0; i < 4; i++) {
    gl2lds16(aSrc[i], &As[0][(i * 256 + w * 64) * 8]);
    gl2lds16(bSrc[i], &Bs[0][(i * 256 + w * 64) * 8]);
  }
  floatx4 acc[4][4] = {};
  int nT = Ksz >> 6;
  for (int t = 0; t < nT; t++) {
    __syncthreads();
    int cur = t & 1;
    if (t + 1 < nT) {
      int nxt = cur ^ 1, ko = (t + 1) * 64;
#pragma unroll
      for (int i = 0; i < 4; i++) {
        gl2lds16(aSrc[i] + ko, &As[nxt][(i * 256 + w * 64) * 8]);
        gl2lds16(bSrc[i] + ko, &Bs[nxt][(i * 256 + w * 64) * 8]);
      }
    }
#pragma unroll
    for (int kk = 0; kk < 2; kk++) {
      int j = kk * 4 + q4;
      bf16x8 af[4], bg[4];
#pragma unroll
      for (int mt = 0; mt < 4; mt++) {
        int r = wm + mt * 16 + ml;
        af[mt] = *reinterpret_cast<const bf16x8*>(&As[cur][r * 64 + (j ^ sw) * 8]);
      }
#pragma unroll
      for (int nt = 0; nt < 4; nt++) {
        int r = wn + nt * 16 + ml;
        bg[nt] = *reinterpret_cast<const bf16x8*>(&Bs[cur][r * 64 + (j ^ sw) * 8]);
      }
#pragma unroll
      for (int mt = 0; mt < 4; mt++)
#pragma unroll
        for (int nt = 0; nt < 4; nt++)
          acc[mt][nt] = __builtin_amdgcn_mfma_f32_16x16x32_bf16(af[mt], bg[nt], acc[mt][nt], 0, 0, 0);
    }
  }
  __syncthreads();
  float (*sred)[2] = (float (*)[2]) & As[0][0];
  float (*sred2)[2] = (float (*)[2]) & Bs[0][0];
  float mx[4][4];
#pragma unroll
  for (int mt = 0; mt < 4; mt++)
#pragma unroll
    for (int r = 0; r < 4; r++)
      mx[mt][r] = fmaxf(fmaxf(acc[mt][0][r], acc[mt][1][r]), fmaxf(acc[mt][2][r], acc[mt][3][r]));
#pragma unroll
  for (int off = 1; off < 16; off <<= 1)
#pragma unroll
    for (int mt = 0; mt < 4; mt++)
#pragma unroll
      for (int r = 0; r < 4; r++) mx[mt][r] = fmaxf(mx[mt][r], __shfl_xor(mx[mt][r], off, 64));
  if (ml == 0)
#pragma unroll
    for (int mt = 0; mt < 4; mt++)
#pragma unroll
      for (int r = 0; r < 4; r++) sred[wm + mt * 16 + q4 * 4 + r][w >> 1] = mx[mt][r];
  __syncthreads();
  float sm[4][4];
#pragma unroll
  for (int mt = 0; mt < 4; mt++)
#pragma unroll
    for (int r = 0; r < 4; r++) {
      int row = wm + mt * 16 + q4 * 4 + r;
      float fm = fmaxf(sred[row][0], sred[row][1]);
      float s = 0.f;
#pragma unroll
      for (int nt = 0; nt < 4; nt++) s += expf(acc[mt][nt][r] - fm);
      sm[mt][r] = s;
    }
#pragma unroll
  for (int off = 1; off < 16; off <<= 1)
#pragma unroll
    for (int mt = 0; mt < 4; mt++)
#pragma unroll
      for (int r = 0; r < 4; r++) sm[mt][r] += __shfl_xor(sm[mt][r], off, 64);
  if (ml == 0)
#pragma unroll
    for (int mt = 0; mt < 4; mt++)
#pragma unroll
      for (int r = 0; r < 4; r++) sred2[wm + mt * 16 + q4 * 4 + r][w >> 1] = sm[mt][r];
  __syncthreads();
  if (tid < 128) {
    float fm = fmaxf(sred[tid][0], sred[tid][1]);
    stM[(size_t)(m0 + tid) * nch + blockIdx.x] = fm;
    stS[(size_t)(m0 + tid) * nch + blockIdx.x] = sred2[tid][0] + sred2[tid][1];
  }
}

// ---------------- combine chunk stats -> lse per row ----------------
__global__ void lse_reduce_kernel(const float* __restrict__ statsM,
                                  const float* __restrict__ statsS,
                                  float* __restrict__ lse, int nch) {
  int row = blockIdx.x, t = threadIdx.x;
  float m = -INFINITY, s = 0.f;
  for (int c = t; c < nch; c += blockDim.x) {
    float cm = statsM[(size_t)row * nch + c];
    float cs = statsS[(size_t)row * nch + c];
    float M = fmaxf(m, cm);
    s = s * expf(m - M) + cs * expf(cm - M);
    m = M;
  }
  __shared__ float sm[256], ss[256];
  sm[t] = m;
  ss[t] = s;
  __syncthreads();
  for (int o = 128; o > 0; o >>= 1) {
    if (t < o) {
      float m2 = sm[t + o], s2 = ss[t + o];
      float M = fmaxf(sm[t], m2);
      float sc = ss[t] * expf(sm[t] - M) + s2 * expf(m2 - M);
      sm[t] = M;
      ss[t] = sc;
    }
    __syncthreads();
  }
  if (t == 0) lse[row] = sm[0] + logf(ss[0]);
}

// ---------------- logit at target ----------------
__global__ void logit_tgt_kernel(const short* __restrict__ V, const short* __restrict__ Eb,
                                 const int* __restrict__ tgt, float* __restrict__ lt,
                                 int E, int Nn, int KN, int LM) {
  int row = blockIdx.x;
  int b = row / Nn;
  int i = (row - b * Nn) / KN;
  int g = tgt[b * LM + i];
  __shared__ float sdata[8];
  float v = b2f(V[(size_t)row * E + threadIdx.x]) * b2f(Eb[(size_t)g * E + threadIdx.x]);
  float s = block_sum(v, sdata);
  if (threadIdx.x == 0) lt[row] = s;
}

// ---------------- final ----------------
__global__ void final_kernel(const float* __restrict__ lt, const float* __restrict__ lse,
                             float* __restrict__ out, int LM, int KN) {
  int b = blockIdx.x, i = threadIdx.x;
  int base = (b * LM + i) * KN;
  float m = -INFINITY;
  for (int k = 0; k < KN; k++) m = fmaxf(m, lt[base + k] - lse[base + k]);
  float s = 0.f;
  for (int k = 0; k < KN; k++) s += expf(lt[base + k] - lse[base + k] - m);
  float cent = m + logf(s) - logf((float)KN);
#pragma unroll
  for (int o = 32; o > 0; o >>= 1) cent += __shfl_down(cent, o, 64);
  if (i == 0) out[b] = -cent / LM;
}

// ---------------- host dispatchers ----------------
// cfg: 0 = 128x128, 1 = 128x64, 2 = 64x64
static inline void bgemm(hipStream_t st, int cfg, const short* A, int lda, long sA,
                         const short* B, int ldb, long sB,
                         void* C, int ldc, long sC, int M, int N, int Ksz, int nb,
                         float alpha, const float* bias, int relu, int out_bf16,
                         int shiftA, int shiftB, int nsplit, int Lroll) {
  dim3 block(256);
  if (cfg == 0) {
    dim3 grid(N / 128, M / 128, nb);
    if (out_bf16)
      bgemm_kernel<128, 128, 1><<<grid, block, 0, st>>>(A, lda, sA, B, ldb, sB, C, ldc, sC, Ksz, alpha, bias, relu, shiftA, shiftB, nsplit, Lroll);
    else
      bgemm_kernel<128, 128, 0><<<grid, block, 0, st>>>(A, lda, sA, B, ldb, sB, C, ldc, sC, Ksz, alpha, bias, relu, shiftA, shiftB, nsplit, Lroll);
  } else if (cfg == 1) {
    dim3 grid(N / 64, M / 128, nb);
    if (out_bf16)
      bgemm_kernel<128, 64, 1><<<grid, block, 0, st>>>(A, lda, sA, B, ldb, sB, C, ldc, sC, Ksz, alpha, bias, relu, shiftA, shiftB, nsplit, Lroll);
    else
      bgemm_kernel<128, 64, 0><<<grid, block, 0, st>>>(A, lda, sA, B, ldb, sB, C, ldc, sC, Ksz, alpha, bias, relu, shiftA, shiftB, nsplit, Lroll);
  } else {
    dim3 grid(N / 64, M / 64, nb);
    if (out_bf16)
      bgemm_kernel<64, 64, 1><<<grid, block, 0, st>>>(A, lda, sA, B, ldb, sB, C, ldc, sC, Ksz, alpha, bias, relu, shiftA, shiftB, nsplit, Lroll);
    else
      bgemm_kernel<64, 64, 0><<<grid, block, 0, st>>>(A, lda, sA, B, ldb, sB, C, ldc, sC, Ksz, alpha, bias, relu, shiftA, shiftB, nsplit, Lroll);
  }
}

static inline void cvtT2(hipStream_t st, const float* src, short* dst, int R, int C,
                         int ldS, int ldD, long sS, long sD, int nb) {
  dim3 grid(C / 32, R / 32, nb), block(32, 8);
  cvtT2_kernel<<<grid, block, 0, st>>>(src, dst, ldS, ldD, sS, sD);
}

extern "C" void kernel_launch(void* const* d_in, const int* in_sizes, int n_in,
                              void* d_out, int out_size, void* d_ws, size_t ws_size,
                              hipStream_t stream) {
  const int* masked = (const int*)d_in[0];
  const int* unmasked = (const int*)d_in[1];
  const int* mask = (const int*)d_in[2];
  const float* embed = (const float*)d_in[3];
  const float* Wt = (const float*)d_in[4];
  const float* bt = (const float*)d_in[5];
  const float* Wtc = (const float*)d_in[6];
  const float* Wq = (const float*)d_in[7];
  const float* Wd = (const float*)d_in[8];
  const float* Wo = (const float*)d_in[9];
  const float* Wu = (const float*)d_in[10];
  const float* Wem = (const float*)d_in[11];
  const float* Wkc = (const float*)d_in[12];
  const float* bkc = (const float*)d_in[13];

  const int B = out_size;                  // 4
  const int BL = in_sizes[0];              // 2048
  const int L = BL / B;                    // 512
  const int BLM = in_sizes[2];             // 256
  const int LM = BLM / B;                  // 64
  const int E = in_sizes[4] / in_sizes[5]; // 256
  const int D = in_sizes[5] / E;           // 6
  const int G = in_sizes[3] / E;           // 32000
  const int K = in_sizes[7] / (D * E * E); // 8
  const int KN = in_sizes[12] / (E * E);   // 4
  const int KE = K * E;                    // 2048
  const int N = LM * KN;                   // 256
  const float inv_sqrt_e = 1.0f / sqrtf((float)E);
  const int nch = G / 128;                 // 250
  const int E3 = 3 * E;                    // 768

  // ---- workspace carve ----
  char* base = (char*)d_ws;
  size_t off = 0;
  auto carve = [&](size_t bytes) {
    char* p = base + off;
    off += (bytes + 255) & ~(size_t)255;
    return p;
  };
  float* xsa = (float*)carve((size_t)BL * E * 4);
  float* xsad = (float*)carve((size_t)BL * E * 4);
  float* xid = (float*)carve((size_t)BL * E * 4);
  float* stM = (float*)carve((size_t)B * N * nch * 4);
  float* stS = (float*)carve((size_t)B * N * nch * 4);
  float* lse = (float*)carve((size_t)B * N * 4);
  float* lt = (float*)carve((size_t)B * N * 4);
  int* tgt = (int*)carve((size_t)B * LM * 4);
  short* xsa_bf = (short*)carve((size_t)BL * E * 2);
  short* xsaT_bf = (short*)carve((size_t)B * E * L * 2);
  short* t3 = (short*)carve((size_t)BL * E3 * 2);          // [t1a | t1b | z]
  short* qy_bf = (short*)carve((size_t)BL * KE * 2);       // q, then y (flash in-place)
  short* r_bf = (short*)carve((size_t)BL * KE * 2);        // relu(y@WdT)
  short* wd_all = (short*)carve((size_t)D * KE * KE * 2);
  short* wq_all = (short*)carve((size_t)D * KE * E * 2);
  short* woT_all = (short*)carve((size_t)D * E * KE * 2);
  short* Bcat1 = (short*)carve((size_t)D * 2 * E * E * 2); // [wtT; wtc], ld E
  short* Bcat2 = (short*)carve((size_t)D * E * E3 * 2);    // [wtcT | wt | wu], ld 3E
  short* embed_bf = (short*)carve((size_t)G * E * 2);
  short* WemT_bf = (short*)carve((size_t)E * E * 2);
  short* Wkc_bf = (short*)carve((size_t)KN * E * E * 2);
  short* gram_bf = (short*)carve((size_t)B * E * E * 2);
  short* xx_bf = (short*)carve((size_t)B * N * E * 2);
  short* xx2_bf = (short*)carve((size_t)B * N * E * 2);
  short* vv_bf = (short*)carve((size_t)B * N * E * 2);
  short* lptok_bf = (short*)carve((size_t)BLM * E * 2);

  // ---- up-front conversions (merged) ----
  {
    long n0 = (long)G * E / 4, n1 = (long)D * KE * KE / 4;
    long n2 = (long)D * KE * E / 4, n3 = (long)KN * E * E / 4;
    long tot = n0 + n1 + n2 + n3;
    cvt4_kernel<<<(int)((tot + 255) / 256), 256, 0, stream>>>(
        embed, embed_bf, n0, Wd, wd_all, n1, Wq, wq_all, n2, Wkc, Wkc_bf, n3);
  }
  cvtT2(stream, Wem, WemT_bf, E, E, E, E, 0, 0, 1);
  cvtT2(stream, Wo, woT_all, KE, E, E, KE, (long)KE * E, (long)E * KE, D);
  {
    dim3 grid(E / 32, E / 32, D), block(32, 8);
    prep_trans_kernel<<<grid, block, 0, stream>>>(Wt, Wtc, Wu, Bcat1, Bcat2, E);
  }

  // z = norm(embed[masked]); xsa = z (+bf16, +transposed, +t3 z-slot)
  embed_norm_kernel<<<BL, E, 0, stream>>>(masked, embed, xsa, xsa_bf, xsaT_bf, t3, E, L);

  for (int d = 0; d < D; d++) {
    const float* btl = bt + (size_t)d * E;
    // t3[:,0:512] = [relu(roll(xsa,+1)@wt) | relu(roll(xsa,-1)@wtcT)]
    bgemm(stream, 2, xsa_bf, E, 0, Bcat1 + (size_t)d * 2 * E * E, E, 0,
          t3, E3, 0, BL, 2 * E, E, 1, 1.f, nullptr, 1, 1, -1, +1, E, L);
    // xsad = t3 @ [wtc; wtT; wuT] + bt   (fp32)
    bgemm(stream, 2, t3, E3, 0, Bcat2 + (size_t)d * E * E3, E3, 0,
          xsad, E, 0, BL, E, E3, 1, 1.f, btl, 0, 0, 0, 0, 0, L);
    // q = xsa @ wq^T
    bgemm(stream, 1, xsa_bf, E, 0, wq_all + (size_t)d * KE * E, E, 0,
          qy_bf, KE, 0, BL, KE, E, 1, 1.f, nullptr, 0, 1, 0, 0, 0, L);
    // fused attention: y = softmax(q.xsa^T/sqrt(E)) @ xsa, in-place over qy
    {
      dim3 grid(L * K / 64, B), block(256);
      flash_kernel<<<grid, block, 0, stream>>>(qy_bf, xsa_bf, xsaT_bf, inv_sqrt_e, L, E, K);
    }
    // r = relu(y @ wd^T)
    bgemm(stream, 1, qy_bf, KE, 0, wd_all + (size_t)d * KE * KE, KE, 0,
          r_bf, KE, 0, BL, KE, KE, 1, 1.f, nullptr, 1, 1, 0, 0, 0, L);
    // xid = r @ wo (fp32)
    bgemm(stream, 2, r_bf, KE, 0, woT_all + (size_t)d * E * KE, KE, 0,
          xid, E, 0, BL, E, KE, 1, 1.f, nullptr, 0, 0, 0, 0, 0, L);
    addnorm_kernel<<<BL, E, 0, stream>>>(xsad, xid, xsa, xsa_bf, xsaT_bf, E, L);
  }

  // ---- head ----
  gather_kernel<<<BLM, E, 0, stream>>>(xsa, mask, unmasked, lptok_bf, tgt, L, LM, E);
  bgemm(stream, 2, xsaT_bf, L, (long)E * L, xsaT_bf, L, (long)E * L,
        gram_bf, E, (long)E * E, E, E, L, B, 1.f, nullptr, 0, 1, 0, 0, 0, L);
  bgemm(stream, 2, lptok_bf, E, 0, Wkc_bf, E, 0, xx_bf, KN * E, 0, BLM, KN * E, E, 1,
        1.f, bkc, 0, 1, 0, 0, 0, L);
  bgemm(stream, 2, xx_bf, E, (long)N * E, gram_bf, E, (long)E * E,
        xx2_bf, E, (long)N * E, N, E, E, B, 1.f, nullptr, 0, 1, 0, 0, 0, L);
  bgemm(stream, 2, xx2_bf, E, 0, WemT_bf, E, 0, vv_bf, E, 0, B * N, E, E, 1,
        1.f, nullptr, 0, 1, 0, 0, 0, L);
  head_stats_kernel<<<dim3(nch, (B * N) / 128), 256, 0, stream>>>(vv_bf, embed_bf, stM, stS, E, nch);
  lse_reduce_kernel<<<B * N, 256, 0, stream>>>(stM, stS, lse, nch);
  logit_tgt_kernel<<<B * N, E, 0, stream>>>(vv_bf, embed_bf, tgt, lt, E, N, KN, LM);
  final_kernel<<<B, LM, 0, stream>>>(lt, lse, (float*)d_out, LM, KN);
}